// Round 11
// baseline (24.347 us; speedup 1.0000x reference)
//
#include <hip/hip_runtime.h>
#include <math.h>

#define T_DIM    2048
#define ROW_IN   28          // M*K*C = 2*7*2
#define ROW_OUT  181         // 28 + 91 + 28 + 28 + 6
#define EPSF     1e-6f
#define R_BLK    32          // rows per block
#define SLOTS    (R_BLK + 2)               // staged rows incl. 2 history
#define IN_STRIDE 30                        // padded LDS row stride (floats)
#define OUT_FLOATS (R_BLK * ROW_OUT)       // 5792
#define OUT_F4     (OUT_FLOATS / 4)        // 1448
#define STAGE_F4   (SLOTS * 7)             // 238 f4 loads per block
#define CVA_ITEMS  (R_BLK * 7)             // 224
#define DIST_ITEMS (R_BLK * 91)            // 2912
#define BODY_ITEMS (R_BLK * 6)             // 192

typedef float vf4 __attribute__((ext_vector_type(4)));   // native vector for NT stores

// packed (i | j<<8) for triu_indices(14, k=1), row-major
__constant__ unsigned short d_pair[91] = {
    0x0100,0x0200,0x0300,0x0400,0x0500,0x0600,0x0700,0x0800,0x0900,0x0A00,0x0B00,0x0C00,0x0D00,
    0x0201,0x0301,0x0401,0x0501,0x0601,0x0701,0x0801,0x0901,0x0A01,0x0B01,0x0C01,0x0D01,
    0x0302,0x0402,0x0502,0x0602,0x0702,0x0802,0x0902,0x0A02,0x0B02,0x0C02,0x0D02,
    0x0403,0x0503,0x0603,0x0703,0x0803,0x0903,0x0A03,0x0B03,0x0C03,0x0D03,
    0x0504,0x0604,0x0704,0x0804,0x0904,0x0A04,0x0B04,0x0C04,0x0D04,
    0x0605,0x0705,0x0805,0x0905,0x0A05,0x0B05,0x0C05,0x0D05,
    0x0706,0x0806,0x0906,0x0A06,0x0B06,0x0C06,0x0D06,
    0x0807,0x0907,0x0A07,0x0B07,0x0C07,0x0D07,
    0x0908,0x0A08,0x0B08,0x0C08,0x0D08,
    0x0A09,0x0B09,0x0C09,0x0D09,
    0x0B0A,0x0C0A,0x0D0A,
    0x0C0B,0x0D0B,
    0x0D0C
};

__global__ __launch_bounds__(256)
void feat_kernel(const float* __restrict__ x, float* __restrict__ out)
{
    __shared__ float in_lds[SLOTS * IN_STRIDE];    // 4080 B (rows g0-2 .. g0+31)
    __shared__ unsigned int tbl[91];               // packed byte-offsets (i*8 | (j*8)<<16)
    __shared__ float out_lds[OUT_FLOATS];          // 23168 B, exact global tile layout

    const int tid = threadIdx.x;
    const int g0  = blockIdx.x * R_BLK;
    const vf4* __restrict__ x4 = (const vf4*)x;

    // ---- Phase 0: stage 34 input rows + pair table into LDS ----
    if (tid < STAGE_F4) {
        int sg = (g0 - 2) * 7 + tid;               // global f4 index, <0 only for block 0
        if (sg < 0) sg = 0;                        // harmless clamp (values masked later)
        vf4 v = x4[sg];
        int s = tid / 7;                           // slot 0..33
        int k = tid - 7 * s;
        float* dst = &in_lds[s * IN_STRIDE + 4 * k];
        ((float2*)dst)[0] = make_float2(v.x, v.y);
        ((float2*)dst)[1] = make_float2(v.z, v.w);
    }
    if (tid < 91) {
        unsigned v = d_pair[tid];
        tbl[tid] = ((v & 0xFFu) * 8u) | (((v >> 8) * 8u) << 16);
    }

    __syncthreads();   // staging complete

    // ---- Phase 1: copy + velocity + acceleration (all reads from LDS) ----
    if (tid < CVA_ITEMS) {
        int r = tid / 7;                           // row 0..31
        int k = tid - 7 * r;                       // f4 column 0..6
        int t = (g0 + r) & (T_DIM - 1);
        const float* cr = &in_lds[(r + 2) * IN_STRIDE + 4 * k];
        const float* pr = &in_lds[(r + 1) * IN_STRIDE + 4 * k];
        const float* qr = &in_lds[(r    ) * IN_STRIDE + 4 * k];
        float2 ca = *(const float2*)cr,  cb2 = *(const float2*)(cr + 2);
        float2 pa = *(const float2*)pr,  pb2 = *(const float2*)(pr + 2);
        float2 qa = *(const float2*)qr,  qb2 = *(const float2*)(qr + 2);
        float c[4] = {ca.x, ca.y, cb2.x, cb2.y};
        float p[4] = {pa.x, pa.y, pb2.x, pb2.y};
        float q[4] = {qa.x, qa.y, qb2.x, qb2.y};
        float* orow = &out_lds[r * ROW_OUT];
        int cb = 4 * k;
        #pragma unroll
        for (int e = 0; e < 4; ++e) {
            float v1 = c[e] - p[e];
            float a2 = c[e] - 2.0f * p[e] + q[e];
            float vv = (t >= 1) ? v1 : 0.0f;
            float aa = (t >= 2) ? a2 : ((t == 1) ? v1 : 0.0f);
            orow[cb + e]       = c[e];      // raw copy  [0,28)
            orow[119 + cb + e] = vv;        // velocity  [119,147)
            orow[147 + cb + e] = aa;        // accel     [147,175)
        }
    }

    // ---- Phase 2: pairwise distances (LDS table + f2 LDS reads) ----
    {
        const char* ldsb = (const char*)in_lds;
        #pragma unroll
        for (int it = 0; it < 12; ++it) {
            int w = tid + it * 256;
            if (it == 11 && w >= DIST_ITEMS) break;
            int r = w & (R_BLK - 1);
            int p = w >> 5;                        // 0..90
            unsigned off = tbl[p];
            int rb = (r + 2) * (IN_STRIDE * 4);    // row base in bytes
            float2 a = *(const float2*)(ldsb + rb + (off & 0xFFFFu));
            float2 b = *(const float2*)(ldsb + rb + (off >> 16));
            float dx = a.x - b.x;
            float dy = a.y - b.y;
            out_lds[r * ROW_OUT + 28 + p] = sqrtf(dx * dx + dy * dy);
        }
    }

    // ---- Phase 3: body features [175,181) ----
    if (tid < BODY_ITEMS) {
        int r   = tid & (R_BLK - 1);
        int idx = tid >> 5;                        // 0..5
        int m   = idx >= 3 ? 1 : 0;
        int q   = idx - 3 * m;
        const float* row = &in_lds[(r + 2) * IN_STRIDE];
        const float* pr  = row + m * 14;
        float val;
        if (q == 0) {
            float dx = pr[0] - pr[12], dy = pr[1] - pr[13];
            val = sqrtf(dx * dx + dy * dy);
        } else if (q == 1) {
            if (m == 0) val = 0.0f;
            else {
                float d1x = row[14] - row[26], d1y = row[15] - row[27];
                float d0x = row[0]  - row[12], d0y = row[1]  - row[13];
                val = sqrtf(d1x*d1x + d1y*d1y) - sqrtf(d0x*d0x + d0y*d0y);
            }
        } else {
            float v1x = pr[0]  - pr[6], v1y = pr[1]  - pr[7];
            float v2x = pr[12] - pr[6], v2y = pr[13] - pr[7];
            float n1 = sqrtf(v1x*v1x + v1y*v1y) + EPSF;
            float n2 = sqrtf(v2x*v2x + v2y*v2y) + EPSF;
            float cosang = (v1x*v2x + v1y*v2y) / (n1 * n2);
            cosang = fminf(fmaxf(cosang, -1.0f + EPSF), 1.0f - EPSF);
            val = acosf(cosang);
        }
        out_lds[r * ROW_OUT + 175 + idx] = val;
    }

    __syncthreads();   // out tile complete

    // ---- Phase 4: coalesced non-temporal f4 store of the whole tile ----
    {
        const vf4* __restrict__ o4 = (const vf4*)out_lds;
        vf4* __restrict__ g4 = (vf4*)out + (size_t)blockIdx.x * OUT_F4;
        #pragma unroll
        for (int it = 0; it < 5; ++it)
            __builtin_nontemporal_store(o4[tid + it * 256], &g4[tid + it * 256]);
        if (tid < OUT_F4 - 5 * 256)
            __builtin_nontemporal_store(o4[tid + 5 * 256], &g4[tid + 5 * 256]);
    }
}

extern "C" void kernel_launch(void* const* d_in, const int* in_sizes, int n_in,
                              void* d_out, int out_size, void* d_ws, size_t ws_size,
                              hipStream_t stream)
{
    const float* x = (const float*)d_in[0];
    float* out = (float*)d_out;
    int n_rows = in_sizes[0] / ROW_IN;     // 131072
    int grid = n_rows / R_BLK;             // 4096 blocks
    feat_kernel<<<grid, 256, 0, stream>>>(x, out);
}

// Round 12
// 22.312 us; speedup vs baseline: 1.0912x; 1.0912x over previous
//
#include <hip/hip_runtime.h>
#include <math.h>

#define T_DIM    2048
#define ROW_IN   28          // M*K*C = 2*7*2
#define ROW_OUT  181         // 28 + 91 + 28 + 28 + 6
#define EPSF     1e-6f
#define R_BLK    16          // rows per block
#define SLOTS    (R_BLK + 2)               // staged rows incl. 2 history
#define IN_STRIDE 30                        // padded LDS row stride (floats)
#define OUT_FLOATS (R_BLK * ROW_OUT)       // 2896
#define OUT_F4     (OUT_FLOATS / 4)        // 724
#define STAGE_F4   (SLOTS * 7)             // 126 f4 loads per block
#define CVA_ITEMS  (R_BLK * 7)             // 112
#define DIST_ITEMS (R_BLK * 91)            // 1456
#define BODY_ITEMS (R_BLK * 6)             // 96

typedef float vf4 __attribute__((ext_vector_type(4)));   // native vector for NT stores

// packed (i | j<<8) for triu_indices(14, k=1), row-major
__constant__ unsigned short d_pair[91] = {
    0x0100,0x0200,0x0300,0x0400,0x0500,0x0600,0x0700,0x0800,0x0900,0x0A00,0x0B00,0x0C00,0x0D00,
    0x0201,0x0301,0x0401,0x0501,0x0601,0x0701,0x0801,0x0901,0x0A01,0x0B01,0x0C01,0x0D01,
    0x0302,0x0402,0x0502,0x0602,0x0702,0x0802,0x0902,0x0A02,0x0B02,0x0C02,0x0D02,
    0x0403,0x0503,0x0603,0x0703,0x0803,0x0903,0x0A03,0x0B03,0x0C03,0x0D03,
    0x0504,0x0604,0x0704,0x0804,0x0904,0x0A04,0x0B04,0x0C04,0x0D04,
    0x0605,0x0705,0x0805,0x0905,0x0A05,0x0B05,0x0C05,0x0D05,
    0x0706,0x0806,0x0906,0x0A06,0x0B06,0x0C06,0x0D06,
    0x0807,0x0907,0x0A07,0x0B07,0x0C07,0x0D07,
    0x0908,0x0A08,0x0B08,0x0C08,0x0D08,
    0x0A09,0x0B09,0x0C09,0x0D09,
    0x0B0A,0x0C0A,0x0D0A,
    0x0C0B,0x0D0B,
    0x0D0C
};

__global__ __launch_bounds__(256)
void feat_kernel(const float* __restrict__ x, float* __restrict__ out)
{
    __shared__ float in_lds[SLOTS * IN_STRIDE];    // 2160 B (rows g0-2 .. g0+15)
    __shared__ unsigned int tbl[91];               // packed byte-offsets (i*8 | (j*8)<<16)
    __shared__ float out_lds[OUT_FLOATS];          // 11584 B, exact global tile layout

    const int tid = threadIdx.x;
    const int g0  = blockIdx.x * R_BLK;
    const vf4* __restrict__ x4 = (const vf4*)x;

    // ---- Phase 0: stage 18 input rows + pair table into LDS ----
    if (tid < STAGE_F4) {
        int sg = (g0 - 2) * 7 + tid;               // global f4 index, <0 only for block 0
        if (sg < 0) sg = 0;                        // harmless clamp (values masked later)
        vf4 v = x4[sg];
        int s = tid / 7;                           // slot 0..17
        int k = tid - 7 * s;
        float* dst = &in_lds[s * IN_STRIDE + 4 * k];
        ((float2*)dst)[0] = make_float2(v.x, v.y);
        ((float2*)dst)[1] = make_float2(v.z, v.w);
    } else if (tid >= 128 && tid < 128 + 91) {
        unsigned v = d_pair[tid - 128];
        tbl[tid - 128] = ((v & 0xFFu) * 8u) | (((v >> 8) * 8u) << 16);
    }

    __syncthreads();   // staging complete

    // ---- Phase 1: copy + velocity + acceleration (all reads from LDS) ----
    if (tid < CVA_ITEMS) {
        int r = tid / 7;                           // row 0..15
        int k = tid - 7 * r;                       // f4 column 0..6
        int t = (g0 + r) & (T_DIM - 1);
        const float* cr = &in_lds[(r + 2) * IN_STRIDE + 4 * k];
        const float* pr = &in_lds[(r + 1) * IN_STRIDE + 4 * k];
        const float* qr = &in_lds[(r    ) * IN_STRIDE + 4 * k];
        float2 ca = *(const float2*)cr,  cb2 = *(const float2*)(cr + 2);
        float2 pa = *(const float2*)pr,  pb2 = *(const float2*)(pr + 2);
        float2 qa = *(const float2*)qr,  qb2 = *(const float2*)(qr + 2);
        float c[4] = {ca.x, ca.y, cb2.x, cb2.y};
        float p[4] = {pa.x, pa.y, pb2.x, pb2.y};
        float q[4] = {qa.x, qa.y, qb2.x, qb2.y};
        float* orow = &out_lds[r * ROW_OUT];
        int cb = 4 * k;
        #pragma unroll
        for (int e = 0; e < 4; ++e) {
            float v1 = c[e] - p[e];
            float a2 = c[e] - 2.0f * p[e] + q[e];
            float vv = (t >= 1) ? v1 : 0.0f;
            float aa = (t >= 2) ? a2 : ((t == 1) ? v1 : 0.0f);
            orow[cb + e]       = c[e];      // raw copy  [0,28)
            orow[119 + cb + e] = vv;        // velocity  [119,147)
            orow[147 + cb + e] = aa;        // accel     [147,175)
        }
    }

    // ---- Phase 2: pairwise distances (LDS table + f2 LDS reads) ----
    {
        const char* ldsb = (const char*)in_lds;
        #pragma unroll
        for (int it = 0; it < 6; ++it) {
            int w = tid + it * 256;
            if (it == 5 && w >= DIST_ITEMS) break;
            int r = w & (R_BLK - 1);
            int p = w >> 4;                        // 0..90
            unsigned off = tbl[p];
            int rb = (r + 2) * (IN_STRIDE * 4);    // row base in bytes
            float2 a = *(const float2*)(ldsb + rb + (off & 0xFFFFu));
            float2 b = *(const float2*)(ldsb + rb + (off >> 16));
            float dx = a.x - b.x;
            float dy = a.y - b.y;
            out_lds[r * ROW_OUT + 28 + p] = sqrtf(dx * dx + dy * dy);
        }
    }

    // ---- Phase 3: body features [175,181) ----
    if (tid < BODY_ITEMS) {
        int r   = tid & (R_BLK - 1);
        int idx = tid >> 4;                        // 0..5
        int m   = idx >= 3 ? 1 : 0;
        int q   = idx - 3 * m;
        const float* row = &in_lds[(r + 2) * IN_STRIDE];
        const float* pr  = row + m * 14;
        float val;
        if (q == 0) {
            float dx = pr[0] - pr[12], dy = pr[1] - pr[13];
            val = sqrtf(dx * dx + dy * dy);
        } else if (q == 1) {
            if (m == 0) val = 0.0f;
            else {
                float d1x = row[14] - row[26], d1y = row[15] - row[27];
                float d0x = row[0]  - row[12], d0y = row[1]  - row[13];
                val = sqrtf(d1x*d1x + d1y*d1y) - sqrtf(d0x*d0x + d0y*d0y);
            }
        } else {
            float v1x = pr[0]  - pr[6], v1y = pr[1]  - pr[7];
            float v2x = pr[12] - pr[6], v2y = pr[13] - pr[7];
            float n1 = sqrtf(v1x*v1x + v1y*v1y) + EPSF;
            float n2 = sqrtf(v2x*v2x + v2y*v2y) + EPSF;
            float cosang = (v1x*v2x + v1y*v2y) / (n1 * n2);
            cosang = fminf(fmaxf(cosang, -1.0f + EPSF), 1.0f - EPSF);
            val = acosf(cosang);
        }
        out_lds[r * ROW_OUT + 175 + idx] = val;
    }

    __syncthreads();   // out tile complete

    // ---- Phase 4: coalesced non-temporal f4 store of the whole tile ----
    {
        const vf4* __restrict__ o4 = (const vf4*)out_lds;
        vf4* __restrict__ g4 = (vf4*)out + (size_t)blockIdx.x * OUT_F4;
        __builtin_nontemporal_store(o4[tid],       &g4[tid]);
        __builtin_nontemporal_store(o4[tid + 256], &g4[tid + 256]);
        if (tid < OUT_F4 - 512)
            __builtin_nontemporal_store(o4[tid + 512], &g4[tid + 512]);
    }
}

extern "C" void kernel_launch(void* const* d_in, const int* in_sizes, int n_in,
                              void* d_out, int out_size, void* d_ws, size_t ws_size,
                              hipStream_t stream)
{
    const float* x = (const float*)d_in[0];
    float* out = (float*)d_out;
    int n_rows = in_sizes[0] / ROW_IN;     // 131072
    int grid = n_rows / R_BLK;             // 8192 blocks
    feat_kernel<<<grid, 256, 0, stream>>>(x, out);
}

// Round 13
// 21.945 us; speedup vs baseline: 1.1094x; 1.0167x over previous
//
#include <hip/hip_runtime.h>
#include <math.h>

#define T_DIM    2048
#define ROW_IN   28          // M*K*C = 2*7*2
#define ROW_OUT  181         // 28 + 91 + 28 + 28 + 6
#define EPSF     1e-6f
#define NTHR     512         // 8 waves
#define R_BLK    32          // rows per block
#define SLOTS    (R_BLK + 2)               // staged rows incl. 2 history
#define IN_STRIDE 30                        // padded LDS row stride (floats)
#define OUT_FLOATS (R_BLK * ROW_OUT)       // 5792
#define OUT_F4     (OUT_FLOATS / 4)        // 1448
#define STAGE_F4   (SLOTS * 7)             // 238 f4 loads per block
#define CVA_ITEMS  (R_BLK * 7)             // 224
#define DIST_ITEMS (R_BLK * 91)            // 2912
#define BODY_ITEMS (R_BLK * 6)             // 192

typedef float vf4 __attribute__((ext_vector_type(4)));   // native vector for NT stores

// packed (i | j<<8) for triu_indices(14, k=1), row-major
__constant__ unsigned short d_pair[91] = {
    0x0100,0x0200,0x0300,0x0400,0x0500,0x0600,0x0700,0x0800,0x0900,0x0A00,0x0B00,0x0C00,0x0D00,
    0x0201,0x0301,0x0401,0x0501,0x0601,0x0701,0x0801,0x0901,0x0A01,0x0B01,0x0C01,0x0D01,
    0x0302,0x0402,0x0502,0x0602,0x0702,0x0802,0x0902,0x0A02,0x0B02,0x0C02,0x0D02,
    0x0403,0x0503,0x0603,0x0703,0x0803,0x0903,0x0A03,0x0B03,0x0C03,0x0D03,
    0x0504,0x0604,0x0704,0x0804,0x0904,0x0A04,0x0B04,0x0C04,0x0D04,
    0x0605,0x0705,0x0805,0x0905,0x0A05,0x0B05,0x0C05,0x0D05,
    0x0706,0x0806,0x0906,0x0A06,0x0B06,0x0C06,0x0D06,
    0x0807,0x0907,0x0A07,0x0B07,0x0C07,0x0D07,
    0x0908,0x0A08,0x0B08,0x0C08,0x0D08,
    0x0A09,0x0B09,0x0C09,0x0D09,
    0x0B0A,0x0C0A,0x0D0A,
    0x0C0B,0x0D0B,
    0x0D0C
};

__global__ __launch_bounds__(NTHR)
void feat_kernel(const float* __restrict__ x, float* __restrict__ out)
{
    __shared__ float in_lds[SLOTS * IN_STRIDE];    // 4080 B (rows g0-2 .. g0+31)
    __shared__ unsigned int tbl[91];               // packed byte-offsets (i*8 | (j*8)<<16)
    __shared__ float out_lds[OUT_FLOATS];          // 23168 B, exact global tile layout

    const int tid = threadIdx.x;
    const int g0  = blockIdx.x * R_BLK;
    const vf4* __restrict__ x4 = (const vf4*)x;

    // ---- Phase 0: stage 34 input rows + pair table into LDS ----
    if (tid < STAGE_F4) {
        int sg = (g0 - 2) * 7 + tid;               // global f4 index, <0 only for block 0
        if (sg < 0) sg = 0;                        // harmless clamp (values masked later)
        vf4 v = x4[sg];
        int s = tid / 7;                           // slot 0..33
        int k = tid - 7 * s;
        float* dst = &in_lds[s * IN_STRIDE + 4 * k];
        ((float2*)dst)[0] = make_float2(v.x, v.y);
        ((float2*)dst)[1] = make_float2(v.z, v.w);
    } else if (tid >= 256 && tid < 256 + 91) {
        unsigned v = d_pair[tid - 256];
        tbl[tid - 256] = ((v & 0xFFu) * 8u) | (((v >> 8) * 8u) << 16);
    }

    __syncthreads();   // staging complete

    // ---- Phase 1: copy + velocity + acceleration (all reads from LDS) ----
    if (tid < CVA_ITEMS) {
        int r = tid / 7;                           // row 0..31
        int k = tid - 7 * r;                       // f4 column 0..6
        int t = (g0 + r) & (T_DIM - 1);
        const float* cr = &in_lds[(r + 2) * IN_STRIDE + 4 * k];
        const float* pr = &in_lds[(r + 1) * IN_STRIDE + 4 * k];
        const float* qr = &in_lds[(r    ) * IN_STRIDE + 4 * k];
        float2 ca = *(const float2*)cr,  cb2 = *(const float2*)(cr + 2);
        float2 pa = *(const float2*)pr,  pb2 = *(const float2*)(pr + 2);
        float2 qa = *(const float2*)qr,  qb2 = *(const float2*)(qr + 2);
        float c[4] = {ca.x, ca.y, cb2.x, cb2.y};
        float p[4] = {pa.x, pa.y, pb2.x, pb2.y};
        float q[4] = {qa.x, qa.y, qb2.x, qb2.y};
        float* orow = &out_lds[r * ROW_OUT];
        int cb = 4 * k;
        #pragma unroll
        for (int e = 0; e < 4; ++e) {
            float v1 = c[e] - p[e];
            float a2 = c[e] - 2.0f * p[e] + q[e];
            float vv = (t >= 1) ? v1 : 0.0f;
            float aa = (t >= 2) ? a2 : ((t == 1) ? v1 : 0.0f);
            orow[cb + e]       = c[e];      // raw copy  [0,28)
            orow[119 + cb + e] = vv;        // velocity  [119,147)
            orow[147 + cb + e] = aa;        // accel     [147,175)
        }
    }

    // ---- Phase 2: pairwise distances (LDS table + f2 LDS reads) ----
    {
        const char* ldsb = (const char*)in_lds;
        #pragma unroll
        for (int it = 0; it < 6; ++it) {
            int w = tid + it * NTHR;
            if (it == 5 && w >= DIST_ITEMS) break;
            int r = w & (R_BLK - 1);
            int p = w >> 5;                        // 0..90
            unsigned off = tbl[p];
            int rb = (r + 2) * (IN_STRIDE * 4);    // row base in bytes
            float2 a = *(const float2*)(ldsb + rb + (off & 0xFFFFu));
            float2 b = *(const float2*)(ldsb + rb + (off >> 16));
            float dx = a.x - b.x;
            float dy = a.y - b.y;
            out_lds[r * ROW_OUT + 28 + p] = sqrtf(dx * dx + dy * dy);
        }
    }

    // ---- Phase 3: body features [175,181) ----
    if (tid < BODY_ITEMS) {
        int r   = tid & (R_BLK - 1);
        int idx = tid >> 5;                        // 0..5
        int m   = idx >= 3 ? 1 : 0;
        int q   = idx - 3 * m;
        const float* row = &in_lds[(r + 2) * IN_STRIDE];
        const float* pr  = row + m * 14;
        float val;
        if (q == 0) {
            float dx = pr[0] - pr[12], dy = pr[1] - pr[13];
            val = sqrtf(dx * dx + dy * dy);
        } else if (q == 1) {
            if (m == 0) val = 0.0f;
            else {
                float d1x = row[14] - row[26], d1y = row[15] - row[27];
                float d0x = row[0]  - row[12], d0y = row[1]  - row[13];
                val = sqrtf(d1x*d1x + d1y*d1y) - sqrtf(d0x*d0x + d0y*d0y);
            }
        } else {
            float v1x = pr[0]  - pr[6], v1y = pr[1]  - pr[7];
            float v2x = pr[12] - pr[6], v2y = pr[13] - pr[7];
            float n1 = sqrtf(v1x*v1x + v1y*v1y) + EPSF;
            float n2 = sqrtf(v2x*v2x + v2y*v2y) + EPSF;
            float cosang = (v1x*v2x + v1y*v2y) / (n1 * n2);
            cosang = fminf(fmaxf(cosang, -1.0f + EPSF), 1.0f - EPSF);
            val = acosf(cosang);
        }
        out_lds[r * ROW_OUT + 175 + idx] = val;
    }

    __syncthreads();   // out tile complete

    // ---- Phase 4: coalesced non-temporal f4 store of the whole tile ----
    {
        const vf4* __restrict__ o4 = (const vf4*)out_lds;
        vf4* __restrict__ g4 = (vf4*)out + (size_t)blockIdx.x * OUT_F4;
        __builtin_nontemporal_store(o4[tid],        &g4[tid]);
        __builtin_nontemporal_store(o4[tid + NTHR], &g4[tid + NTHR]);
        if (tid < OUT_F4 - 2 * NTHR)
            __builtin_nontemporal_store(o4[tid + 2 * NTHR], &g4[tid + 2 * NTHR]);
    }
}

extern "C" void kernel_launch(void* const* d_in, const int* in_sizes, int n_in,
                              void* d_out, int out_size, void* d_ws, size_t ws_size,
                              hipStream_t stream)
{
    const float* x = (const float*)d_in[0];
    float* out = (float*)d_out;
    int n_rows = in_sizes[0] / ROW_IN;     // 131072
    int grid = n_rows / R_BLK;             // 4096 blocks
    feat_kernel<<<grid, NTHR, 0, stream>>>(x, out);
}